// Round 2
// baseline (110.986 us; speedup 1.0000x reference)
//
#include <hip/hip_runtime.h>
#include <stdint.h>
#include <stddef.h>

#define BB 16
#define TT 2048
#define CC 64

typedef __attribute__((ext_vector_type(8))) short short8;
typedef __attribute__((ext_vector_type(4))) float f32x4;

#if defined(__has_builtin)
#if __has_builtin(__builtin_amdgcn_exp2f)
#define EXP2(x) __builtin_amdgcn_exp2f(x)
#else
#define EXP2(x) exp2f(x)
#endif
#else
#define EXP2(x) exp2f(x)
#endif

// round-to-nearest-even f32 -> bf16 bit pattern
static __device__ __forceinline__ unsigned short f2bf(float f) {
  union { float f; unsigned int u; } v; v.f = f;
  unsigned int u = v.u;
  return (unsigned short)((u + 0x7FFFu + ((u >> 16) & 1u)) >> 16);
}

// ---------------------------------------------------------------------------
// Prep: xb = bf16(x)  [B,T,C];  xbT = bf16(x) transposed [B,C,T];  sq = rowsumsq
// One block per 64x64 (t,c) tile. 256 threads, each handles 16 floats.
// ---------------------------------------------------------------------------
__global__ __launch_bounds__(256) void prep_kernel(
    const float* __restrict__ x, unsigned short* __restrict__ xb,
    unsigned short* __restrict__ xbT, float* __restrict__ sq)
{
  __shared__ float tile[64][65];   // +1 pad breaks transpose bank conflicts
  __shared__ float rs[64][4];
  const int b   = blockIdx.x >> 5;
  const int t0  = (blockIdx.x & 31) << 6;
  const int tid = threadIdx.x;
  const int r   = tid >> 2, qd = tid & 3;

  const float* src = x + ((size_t)(b * TT + t0 + r) * CC + qd * 16);
  float v[16];
  float ssq = 0.f;
#pragma unroll
  for (int k = 0; k < 4; ++k) {
    f32x4 t4 = ((const f32x4*)src)[k];
#pragma unroll
    for (int j = 0; j < 4; ++j) { float f = t4[j]; v[k * 4 + j] = f; ssq += f * f; }
  }

  unsigned short hb[16];
#pragma unroll
  for (int j = 0; j < 16; ++j) hb[j] = f2bf(v[j]);
  unsigned short* dstb = xb + ((size_t)(b * TT + t0 + r) * CC + qd * 16);
  ((short8*)dstb)[0] = *(const short8*)(hb);
  ((short8*)dstb)[1] = *(const short8*)(hb + 8);

#pragma unroll
  for (int j = 0; j < 16; ++j) tile[r][qd * 16 + j] = v[j];
  rs[r][qd] = ssq;
  __syncthreads();

  if (tid < 64)
    sq[(size_t)b * TT + t0 + tid] = rs[tid][0] + rs[tid][1] + rs[tid][2] + rs[tid][3];

  const int c = tid >> 2, tq = tid & 3;
  unsigned short ht[16];
#pragma unroll
  for (int j = 0; j < 16; ++j) ht[j] = f2bf(tile[tq * 16 + j][c]);
  unsigned short* dstT = xbT + ((size_t)(b * CC + c) * TT + t0 + tq * 16);
  ((short8*)dstT)[0] = *(const short8*)(ht);
  ((short8*)dstT)[1] = *(const short8*)(ht + 8);
}

// ---------------------------------------------------------------------------
// Main fused kernel. Block = 256 threads = 4 waves; block tile = 64 q-rows;
// wave tile = 16 q-rows. Iterate 32 KV tiles of 64. 16x16x32 bf16 MFMA.
// LDS K-tile [64s][64c] and V^T-tile [64c][64s], both XOR-swizzled
// (16B-slot ^= row&7) to make ds_read_b128 column reads conflict-free.
// P (exp weights) round-trips through a per-wave swizzled LDS buffer.
// ---------------------------------------------------------------------------
__global__ __launch_bounds__(256, 2) void attn_kernel(
    const float* __restrict__ x, const unsigned short* __restrict__ xb,
    const unsigned short* __restrict__ xbT, const float* __restrict__ sq,
    const float* __restrict__ rsig, const float* __restrict__ marg,
    float* __restrict__ out)
{
  __shared__ unsigned short Klds[2][64 * 64];
  __shared__ unsigned short Vlds[2][64 * 64];
  __shared__ unsigned short Plds[4][16 * 64];

  // bijective XCD swizzle: 512 blocks -> 64 consecutive logical blocks per XCD
  const int bid = ((blockIdx.x & 7) << 6) | (blockIdx.x >> 3);
  const int b   = bid >> 5;
  const int qb  = (bid & 31) << 6;
  const int tid = threadIdx.x;
  const int w = tid >> 6, lane = tid & 63;
  const int hi = lane >> 4, lo = lane & 15;

  const float L2E = 1.44269504088896f;
  const float rl2 = -rsig[0] * L2E;   // exp(-r*d + m) = exp2(d*rl2 + ml2)
  const float ml2 = marg[0] * L2E;

  const unsigned short* xb_b  = xb  + (size_t)b * TT * CC;
  const unsigned short* xbT_b = xbT + (size_t)b * CC * TT;
  const float* sq_b = sq + (size_t)b * TT;

  const int q0 = qb + w * 16;

  // Q A-fragments: lane holds row q0+lo, k = ks*32 + hi*8 + j (contiguous 16B)
  short8 qf[2];
#pragma unroll
  for (int ks = 0; ks < 2; ++ks)
    qf[ks] = *(const short8*)(xb_b + (size_t)(q0 + lo) * CC + ks * 32 + hi * 8);

  float aq[4];
#pragma unroll
  for (int r = 0; r < 4; ++r) aq[r] = sq_b[q0 + hi * 4 + r];

  f32x4 oacc[4];
#pragma unroll
  for (int ct = 0; ct < 4; ++ct) oacc[ct] = (f32x4){0.f, 0.f, 0.f, 0.f};

  // staging assignment: thread covers 16B slot `slot` of row `srow` (and +32)
  const int srow = tid >> 3, slot = tid & 7;
  const int swz0 = srow * 64        + ((slot ^ (srow & 7)) * 8);
  const int swz1 = (srow + 32) * 64 + ((slot ^ (srow & 7)) * 8);

  short8 stg0, stg1, stg2, stg3;

  auto LOADT = [&](int t) {
    const size_t sb = (size_t)t * 64;
    stg0 = *(const short8*)(xb_b  + (sb + srow) * CC + slot * 8);
    stg1 = *(const short8*)(xb_b  + (sb + 32 + srow) * CC + slot * 8);
    stg2 = *(const short8*)(xbT_b + (size_t)srow * TT + sb + slot * 8);
    stg3 = *(const short8*)(xbT_b + (size_t)(srow + 32) * TT + sb + slot * 8);
  };
  auto WRITET = [&](int bf) {
    *(short8*)(&Klds[bf][swz0]) = stg0;
    *(short8*)(&Klds[bf][swz1]) = stg1;
    *(short8*)(&Vlds[bf][swz0]) = stg2;
    *(short8*)(&Vlds[bf][swz1]) = stg3;
  };

  LOADT(0); WRITET(0);
  __syncthreads();

  for (int t = 0; t < 32; ++t) {
    const int cur = t & 1;
    if (t + 1 < 32) LOADT(t + 1);          // prefetch next tile into regs

    const int sb = t * 64;
    float as[4];
#pragma unroll
    for (int ct = 0; ct < 4; ++ct) as[ct] = sq_b[sb + ct * 16 + lo];

    f32x4 sac[4];
#pragma unroll
    for (int ct = 0; ct < 4; ++ct) sac[ct] = (f32x4){0.f, 0.f, 0.f, 0.f};

    // QK^T: B-frag lane: col s = ct*16+lo, k = c = ks*32 + hi*8 + j
#pragma unroll
    for (int ct = 0; ct < 4; ++ct) {
#pragma unroll
      for (int ks = 0; ks < 2; ++ks) {
        const short8 kf = *(const short8*)(
            &Klds[cur][(ct * 16 + lo) * 64 + (((ks * 4 + hi) ^ (lo & 7)) * 8)]);
        sac[ct] = __builtin_amdgcn_mfma_f32_16x16x32_bf16(qf[ks], kf, sac[ct], 0, 0, 0);
      }
    }

    // elementwise kernel + diagonal mask; write bf16 P to per-wave LDS
    const bool dtile = (sb <= q0 + 15) && (q0 <= sb + 63);
#pragma unroll
    for (int ct = 0; ct < 4; ++ct) {
#pragma unroll
      for (int r = 0; r < 4; ++r) {
        float d = aq[r] + as[ct] - 2.f * sac[ct][r];
        d = fmaxf(d, 0.f);
        float kk = EXP2(fmaf(d, rl2, ml2));
        if (dtile && (q0 + hi * 4 + r == sb + ct * 16 + lo)) kk = 0.f;
        const int s = ct * 16 + lo, q = hi * 4 + r;
        Plds[w][q * 64 + (((s >> 3) ^ (q & 7)) * 8) + (s & 7)] = f2bf(kk);
      }
    }

    // PV: A-frag = P (row q = lo, k = s), B-frag = V^T (col c, k = s)
    short8 pf[2];
#pragma unroll
    for (int ks = 0; ks < 2; ++ks)
      pf[ks] = *(const short8*)(
          &Plds[w][lo * 64 + (((ks * 4 + hi) ^ (lo & 7)) * 8)]);

#pragma unroll
    for (int ct = 0; ct < 4; ++ct) {
#pragma unroll
      for (int ks = 0; ks < 2; ++ks) {
        const short8 vf = *(const short8*)(
            &Vlds[cur][(ct * 16 + lo) * 64 + (((ks * 4 + hi) ^ (lo & 7)) * 8)]);
        oacc[ct] = __builtin_amdgcn_mfma_f32_16x16x32_bf16(pf[ks], vf, oacc[ct], 0, 0, 0);
      }
    }

    if (t + 1 < 32) WRITET(cur ^ 1);       // waits its own vmcnt; disjoint buffer
    __syncthreads();
  }

  // epilogue: out = x + O  (C/D layout: col = lo, row = hi*4 + r)
#pragma unroll
  for (int ct = 0; ct < 4; ++ct) {
#pragma unroll
    for (int r = 0; r < 4; ++r) {
      const int q = q0 + hi * 4 + r;
      const int c = ct * 16 + lo;
      const size_t idx = (size_t)(b * TT + q) * CC + c;
      out[idx] = x[idx] + oacc[ct][r];
    }
  }
}

// ---------------------------------------------------------------------------
extern "C" void kernel_launch(void* const* d_in, const int* in_sizes, int n_in,
                              void* d_out, int out_size, void* d_ws, size_t ws_size,
                              hipStream_t stream) {
  const float* x    = (const float*)d_in[0];
  const float* rsig = (const float*)d_in[1];
  const float* marg = (const float*)d_in[2];
  float* out = (float*)d_out;

  unsigned short* xb  = (unsigned short*)d_ws;                 // 4 MB
  unsigned short* xbT = xb + (size_t)BB * TT * CC;             // 4 MB
  float* sq = (float*)(xbT + (size_t)BB * TT * CC);            // 128 KB

  prep_kernel<<<512, 256, 0, stream>>>(x, xb, xbT, sq);
  attn_kernel<<<512, 256, 0, stream>>>(x, xb, xbT, sq, rsig, marg, out);
}

// Round 4
// 100.078 us; speedup vs baseline: 1.1090x; 1.1090x over previous
//
#include <hip/hip_runtime.h>
#include <stdint.h>
#include <stddef.h>

#define BB 16
#define TT 2048
#define CC 64

typedef __attribute__((ext_vector_type(8))) short short8;
typedef __attribute__((ext_vector_type(4))) short s16x4;
typedef __attribute__((ext_vector_type(4))) float f32x4;
typedef __attribute__((ext_vector_type(16))) float f32x16;

#if defined(__has_builtin)
#if __has_builtin(__builtin_amdgcn_exp2f)
#define EXP2(x) __builtin_amdgcn_exp2f(x)
#else
#define EXP2(x) exp2f(x)
#endif
#else
#define EXP2(x) exp2f(x)
#endif

// round-to-nearest-even f32 -> bf16 bit pattern
static __device__ __forceinline__ unsigned short f2bf(float f) {
  union { float f; unsigned int u; } v; v.f = f;
  unsigned int u = v.u;
  return (unsigned short)((u + 0x7FFFu + ((u >> 16) & 1u)) >> 16);
}

// T12 pack: 8 f32 (this lane's half of a 16-k strip) -> PV A-fragment.
// cvt_pk pairs, then permlane32_swap exchanges halves with lane^32 so each
// lane ends up with k = (lane>>5)*8 + j in order.
static __device__ __forceinline__ short8 pack_swap(
    float a0, float a1, float a2, float a3,
    float a4, float a5, float a6, float a7) {
  unsigned X, Z, Y, W;
  asm("v_cvt_pk_bf16_f32 %0, %1, %2" : "=v"(X) : "v"(a0), "v"(a1));
  asm("v_cvt_pk_bf16_f32 %0, %1, %2" : "=v"(Z) : "v"(a2), "v"(a3));
  asm("v_cvt_pk_bf16_f32 %0, %1, %2" : "=v"(Y) : "v"(a4), "v"(a5));
  asm("v_cvt_pk_bf16_f32 %0, %1, %2" : "=v"(W) : "v"(a6), "v"(a7));
  asm("v_permlane32_swap_b32 %0, %1" : "+v"(X), "+v"(Y));
  asm("v_permlane32_swap_b32 %0, %1" : "+v"(Z), "+v"(W));
  union { unsigned u[4]; short8 s; } u;
  u.u[0] = X; u.u[1] = Z; u.u[2] = Y; u.u[3] = W;
  return u.s;
}

// ---------------------------------------------------------------------------
// Prep v2: 2048 blocks (16 b x 128 t-tiles of 16), 256 threads, 4 floats/thr.
// xb = bf16(x) [B,T,C]; xbT = transposed [B,C,T]; sq = row sum of squares.
// ---------------------------------------------------------------------------
__global__ __launch_bounds__(256, 4) void prep_kernel(
    const float* __restrict__ x, unsigned short* __restrict__ xb,
    unsigned short* __restrict__ xbT, float* __restrict__ sq)
{
  __shared__ unsigned short tile[16 * 68];   // [16 t][64 c], pad 68
  const int b   = blockIdx.x >> 7;
  const int t0  = (blockIdx.x & 127) << 4;
  const int tid = threadIdx.x;
  const int r   = tid >> 4;          // 0..15 t-row
  const int cg  = tid & 15;          // c-group
  const int c4  = cg * 4;

  const size_t idx = (size_t)(b * TT + t0 + r) * CC + c4;
  const f32x4 v = *(const f32x4*)(x + idx);
  float ssq = v[0]*v[0] + v[1]*v[1] + v[2]*v[2] + v[3]*v[3];

  s16x4 hv;
  hv[0] = (short)f2bf(v[0]); hv[1] = (short)f2bf(v[1]);
  hv[2] = (short)f2bf(v[2]); hv[3] = (short)f2bf(v[3]);
  *(s16x4*)(xb + idx) = hv;
  *(s16x4*)(&tile[r * 68 + c4]) = hv;

  ssq += __shfl_xor(ssq, 1); ssq += __shfl_xor(ssq, 2);
  ssq += __shfl_xor(ssq, 4); ssq += __shfl_xor(ssq, 8);
  if (cg == 0) sq[(size_t)b * TT + t0 + r] = ssq;
  __syncthreads();

  const int c = tid >> 2, tq = tid & 3;
  s16x4 o;
#pragma unroll
  for (int k = 0; k < 4; ++k) o[k] = (short)tile[(tq * 4 + k) * 68 + c];
  *(s16x4*)(xbT + (size_t)(b * CC + c) * TT + t0 + tq * 4) = o;
}

// ---------------------------------------------------------------------------
// attn v2: block = 4 waves; block tile 64 q-rows x full KV sweep (32 tiles
// of 64 s). Wave (wq,ws) owns the 32q x 32s quadrant. Swapped QK^T
// (mfma(K,Q), 32x32x16) puts P's s-dim in-lane; T12 cvt_pk+permlane32_swap
// builds PV A-frags in registers (no P LDS round-trip). ws-halves of O are
// reduced through LDS at the end.
// ---------------------------------------------------------------------------
__global__ __launch_bounds__(256, 2) void attn_kernel(
    const float* __restrict__ x, const unsigned short* __restrict__ xb,
    const unsigned short* __restrict__ xbT, const float* __restrict__ sq,
    const float* __restrict__ rsig, const float* __restrict__ marg,
    float* __restrict__ out)
{
  __shared__ unsigned short Klds[2][64 * 64];   // [s][c], swizzled 16B slots
  __shared__ unsigned short Vlds[2][64 * 64];   // [c][s], swizzled 16B slots
  __shared__ float Red[2][32 * 64];             // ws=1 partial O per wq

  const int bid = ((blockIdx.x & 7) << 6) | (blockIdx.x >> 3);  // XCD swizzle
  const int b   = bid >> 5;
  const int qb  = (bid & 31) << 6;
  const int tid = threadIdx.x;
  const int w = tid >> 6, lane = tid & 63;
  const int l31 = lane & 31, hi1 = lane >> 5;
  const int wq = w & 1, ws = w >> 1;

  const float L2E = 1.44269504088896f;
  const float rl2 = -rsig[0] * L2E;
  const float ml2 = marg[0] * L2E;

  const unsigned short* xb_b  = xb  + (size_t)b * TT * CC;
  const unsigned short* xbT_b = xbT + (size_t)b * CC * TT;
  const float* sq_b = sq + (size_t)b * TT;

  const int q0w = qb + wq * 32;

  // Q B-fragments: col q = q0w + l31, k = c = kc*16 + hi1*8 + j (16B reads)
  short8 qf[4];
#pragma unroll
  for (int kc = 0; kc < 4; ++kc)
    qf[kc] = *(const short8*)(xb_b + (size_t)(q0w + l31) * CC + kc * 16 + hi1 * 8);
  const float aq = sq_b[q0w + l31];

  f32x16 oacc[2];
#pragma unroll
  for (int ct = 0; ct < 2; ++ct)
#pragma unroll
    for (int i = 0; i < 16; ++i) oacc[ct][i] = 0.f;

  // staging: thread covers 16B slot `slot` of rows srow and srow+32
  const int srow = tid >> 3, slot = tid & 7;
  const int swz0 = srow * 64        + ((slot ^ (srow & 7)) * 8);
  const int swz1 = (srow + 32) * 64 + ((slot ^ (srow & 7)) * 8);

  short8 stg0, stg1, stg2, stg3;
  auto LOADT = [&](int t) {
    const size_t sb = (size_t)t * 64;
    stg0 = *(const short8*)(xb_b  + (sb + srow) * CC + slot * 8);
    stg1 = *(const short8*)(xb_b  + (sb + 32 + srow) * CC + slot * 8);
    stg2 = *(const short8*)(xbT_b + (size_t)srow * TT + sb + slot * 8);
    stg3 = *(const short8*)(xbT_b + (size_t)(srow + 32) * TT + sb + slot * 8);
  };
  auto WRITET = [&](int bf) {
    *(short8*)(&Klds[bf][swz0]) = stg0;
    *(short8*)(&Klds[bf][swz1]) = stg1;
    *(short8*)(&Vlds[bf][swz0]) = stg2;
    *(short8*)(&Vlds[bf][swz1]) = stg3;
  };

  LOADT(0); WRITET(0);
  __syncthreads();

  const int rr = ws * 32 + l31;          // K-row this lane reads (A-frag)
  for (int t = 0; t < 32; ++t) {
    const int cur = t & 1;
    const int tb = t * 64;
    if (t + 1 < 32) LOADT(t + 1);

    // s-row sums of squares (broadcast loads, L1-resident) + aq
    float aqas[16];
#pragma unroll
    for (int r = 0; r < 16; ++r)
      aqas[r] = aq + sq_b[tb + ws * 32 + ((r & 3) + 8 * (r >> 2)) + 4 * hi1];

    // QK^T swapped: D[s][q], A = K rows (s), B = Q cols (q), k = c
    f32x16 sac;
#pragma unroll
    for (int i = 0; i < 16; ++i) sac[i] = 0.f;
#pragma unroll
    for (int kc = 0; kc < 4; ++kc) {
      const short8 kf = *(const short8*)(
          &Klds[cur][rr * 64 + (((kc * 2 + hi1) ^ (rr & 7)) * 8)]);
      sac = __builtin_amdgcn_mfma_f32_32x32x16_bf16(kf, qf[kc], sac, 0, 0, 0);
    }

    // elementwise Gaussian kernel; lane q = l31, s-local = (r&3)+8*(r>>2)+4*hi1
    float p[16];
#pragma unroll
    for (int r = 0; r < 16; ++r) {
      float d = fmaf(sac[r], -2.f, aqas[r]);
      d = fmaxf(d, 0.f);
      p[r] = EXP2(fmaf(d, rl2, ml2));
    }
    if (tb + ws * 32 == qb + wq * 32) {           // diagonal quadrant (uniform)
#pragma unroll
      for (int r = 0; r < 16; ++r) {
        const int sl = (r & 3) + 8 * (r >> 2) + 4 * hi1;
        if (sl == l31) p[r] = 0.f;
      }
    }

    // PV A-frags in-register (T12)
    short8 af0 = pack_swap(p[0], p[1], p[2],  p[3],  p[4],  p[5],  p[6],  p[7]);
    short8 af1 = pack_swap(p[8], p[9], p[10], p[11], p[12], p[13], p[14], p[15]);

    // PV: D[q][c] += P[q][s] * X[s][c]; B-frag from Vlds rows c, k = s
#pragma unroll
    for (int ct = 0; ct < 2; ++ct) {
      const int rowc = ct * 32 + l31;
#pragma unroll
      for (int kk = 0; kk < 2; ++kk) {
        const short8 vf = *(const short8*)(
            &Vlds[cur][rowc * 64 + (((ws * 4 + kk * 2 + hi1) ^ (rowc & 7)) * 8)]);
        oacc[ct] = __builtin_amdgcn_mfma_f32_32x32x16_bf16(
            kk ? af1 : af0, vf, oacc[ct], 0, 0, 0);
      }
    }

    if (t + 1 < 32) WRITET(cur ^ 1);
    __syncthreads();
  }

  // reduce ws halves through LDS; C/D layout: col c = ct*32+l31,
  // row q = (r&3)+8*(r>>2)+4*hi1
  if (ws == 1) {
#pragma unroll
    for (int ct = 0; ct < 2; ++ct)
#pragma unroll
      for (int r = 0; r < 16; ++r) {
        const int ql = (r & 3) + 8 * (r >> 2) + 4 * hi1;
        Red[wq][ql * 64 + ct * 32 + l31] = oacc[ct][r];
      }
  }
  __syncthreads();
  if (ws == 0) {
#pragma unroll
    for (int ct = 0; ct < 2; ++ct)
#pragma unroll
      for (int r = 0; r < 16; ++r) {
        const int ql = (r & 3) + 8 * (r >> 2) + 4 * hi1;
        const int c  = ct * 32 + l31;
        const size_t idx = (size_t)(b * TT + qb + wq * 32 + ql) * CC + c;
        out[idx] = x[idx] + oacc[ct][r] + Red[wq][ql * 64 + c];
      }
  }
}

// ---------------------------------------------------------------------------
extern "C" void kernel_launch(void* const* d_in, const int* in_sizes, int n_in,
                              void* d_out, int out_size, void* d_ws, size_t ws_size,
                              hipStream_t stream) {
  const float* x    = (const float*)d_in[0];
  const float* rsig = (const float*)d_in[1];
  const float* marg = (const float*)d_in[2];
  float* out = (float*)d_out;

  unsigned short* xb  = (unsigned short*)d_ws;                 // 4 MB
  unsigned short* xbT = xb + (size_t)BB * TT * CC;             // 4 MB
  float* sq = (float*)(xbT + (size_t)BB * TT * CC);            // 128 KB

  prep_kernel<<<2048, 256, 0, stream>>>(x, xb, xbT, sq);
  attn_kernel<<<512, 256, 0, stream>>>(x, xb, xbT, sq, rsig, marg, out);
}